// Round 3
// baseline (401.282 us; speedup 1.0000x reference)
//
#include <hip/hip_runtime.h>

// DEChannelPool: 6 soft-morphology branches + per-channel BN + 1x1 conv + BN + ReLU.
// Trick 1: exp(beta*(w±x)) = exp(beta*w)*exp(±beta*x): 2 exps per input pixel (shifted
//          by M for fp32 range), reused across all taps/branches.
// Trick 2: BN+conv fold to alpha*log2(S) + const; const cancels in the final scalar BN.
// R2: register-rotating stencil, split E/D sweeps, EX/EY planes, launch_bounds(256,7).
// R3: kill global atomics in k_reduce_c. 8 chunk-private partial buffers + plain
//     stores (21.3 MB ws, gated on ws_size at runtime with R2 atomic fallback);
//     k_fstats sums the partials. Atomics were 0.7 GB of uncacheable RMW traffic
//     (device-scope coherence point) = ~130 of k_reduce_c's 186 us.

#define BETA 15.0f
#define MSHIFT 25.0f
#define INV_BETA (1.0f/15.0f)
#define LN2 0.6931471805599453f
#define EPSB 1e-5f
#define Hn 192
#define Wn 192
#define HWn (192*192)
#define N1 (8*192*192)
#define HALO 3
#define TILE_W 32
#define TILE_H 64
#define TDW 38              // TILE_W + 2*HALO
#define TDH 70              // TILE_H + 2*HALO
#define TSTRf 39            // TDW + 1 pad (floats)
#define PLANE (TDH*TSTRf)   // 2730 floats
#define NLOAD (TDH*TDW)     // 2660
#define NTW 6               // 192/32
#define NTILES 18           // (192/64) * (192/32)
#define SFLOOR 1e-37f

// workspace layout (float offsets)
#define WS_SUM   0
#define WS_SQS   384
#define WS_SCAL  768
#define WS_ALPHA 772
#define WS_WG    1156
#define WS_YE    4612
#define WS_YD    (4612 + 294912)
#define WS_TOTAL (4612 + 2*294912)              // atomic-fallback footprint
#define WS_PE    WS_TOTAL                        // [8 chunks][8 b][HWn]
#define WS_PD    (WS_TOTAL + 8*294912)
#define WS_TOTAL_P (WS_TOTAL + 16*294912)        // 5,313,028 floats = 21.3 MB

__global__ void k_wexp(const float* __restrict__ we,
                       const float* __restrict__ wd,
                       float* __restrict__ wg) {
    int idx = blockIdx.x * 256 + threadIdx.x;
    if (idx >= 3456) return;
    int kb = idx / 576;            // 0..5 (0-2 erosion, 3-5 dilation)
    int rem = idx - kb * 576;      // c*9 + tap
    float w = (kb < 3) ? we[kb * 576 + rem] : wd[(kb - 3) * 576 + rem];
    wg[idx] = __expf(BETA * w);
}

// Fill the 70x38 halo tile: EX = exp(-bx-M) (erosion), EY = exp(bx-M) (dilation).
__device__ __forceinline__ void load_tile(const float* __restrict__ xp,
                                          float* __restrict__ EX,
                                          float* __restrict__ EY,
                                          int h0, int w0, int tid) {
    const float em0 = __expf(-MSHIFT);
    int r = tid / TDW;
    int cc = tid - r * TDW;
    for (int l = tid; l < NLOAD; l += 256) {
        int gh = h0 - HALO + r, gw = w0 - HALO + cc;
        float ex, ey;
        if ((unsigned)gh < (unsigned)Hn && (unsigned)gw < (unsigned)Wn) {
            float bx = BETA * xp[gh * Wn + gw];
            ex = __expf(-bx - MSHIFT);
            ey = __expf( bx - MSHIFT);
        } else { ex = em0; ey = em0; }    // zero padding -> x=0
        int idx = r * TSTRf + cc;
        EX[idx] = ex;
        EY[idx] = ey;
        r += 6; cc += 28;                 // 256 = 6*38 + 28
        if (cc >= TDW) { cc -= TDW; ++r; }
    }
}

// Register-rotating stencil over ONE plane (one morphology side). Each b32 read
// feeds up to 3 of the 8 output accumulators. All offsets literal after unroll.
template<int D>
__device__ __forceinline__ void sweep(const float* __restrict__ P,
                                      int py0, int px,
                                      const float* __restrict__ wgp,
                                      float* __restrict__ S) {
    float W[9];
#pragma unroll
    for (int k2 = 0; k2 < 9; ++k2) W[k2] = wgp[k2];
#pragma unroll
    for (int k = 0; k < 8; ++k) S[k] = 0.f;
    const float* base = P + (py0 - D + HALO) * TSTRf + (px - D);
#pragma unroll
    for (int r = 0; r < 8 + 2 * D; ++r) {
        float va = base[r * TSTRf];
        float vb = base[r * TSTRf + D];
        float vc = base[r * TSTRf + 2 * D];
#pragma unroll
        for (int i = 0; i < 3; ++i) {
            int k = r - i * D;            // output row fed by input row r via weight-row i
            if (k >= 0 && k < 8) {
                S[k] = fmaf(W[i*3+0], va, S[k]);
                S[k] = fmaf(W[i*3+1], vb, S[k]);
                S[k] = fmaf(W[i*3+2], vc, S[k]);
            }
        }
    }
}

__device__ __forceinline__ void red2(float a, float b2, int lane, float* rs, float* rq) {
#pragma unroll
    for (int off = 32; off; off >>= 1) {
        a  += __shfl_down(a, off, 64);
        b2 += __shfl_down(b2, off, 64);
    }
    if (lane == 0) { *rs = a; *rq = b2; }
}

__global__ __launch_bounds__(256, 7) void k_morph_stats(
    const float* __restrict__ x, const float* __restrict__ wg,
    float* __restrict__ sum, float* __restrict__ sqs) {
    __shared__ float EX[PLANE], EY[PLANE];
    __shared__ float redS[4][6], redQ[4][6];
    const int tid = threadIdx.x;
    const int p = blockIdx.y;            // b*64 + c
    const int c = p & 63;
    const int t = blockIdx.x;
    const int h0 = (t / NTW) * TILE_H, w0 = (t % NTW) * TILE_W;

    load_tile(x + (size_t)p * HWn, EX, EY, h0, w0, tid);
    __syncthreads();

    const int px = (tid & 31) + HALO;
    const int py0 = (tid >> 5) * 8;      // 8-row vertical strip per thread
    const int lane = tid & 63, wv = tid >> 6;

#define DO_SIDE_STATS(D, BR, PL, SGN, SLOT) { \
    float S[8]; \
    sweep<D>(PL, py0, px, wg + (SLOT)*576 + c*9, S); \
    float sv = 0.f, qv = 0.f; \
    _Pragma("unroll") \
    for (int k = 0; k < 8; ++k) { \
        float m = fmaf(__log2f(fmaxf(S[k], SFLOOR)), (SGN)*LN2*INV_BETA, (SGN)*MSHIFT*INV_BETA); \
        sv += m; qv = fmaf(m, m, qv); \
    } \
    red2(sv, qv, lane, &redS[wv][SLOT], &redQ[wv][SLOT]); }

    DO_SIDE_STATS(1, 0, EX, -1.f, 0)
    DO_SIDE_STATS(1, 0, EY,  1.f, 3)
    DO_SIDE_STATS(2, 1, EX, -1.f, 1)
    DO_SIDE_STATS(2, 1, EY,  1.f, 4)
    DO_SIDE_STATS(3, 2, EX, -1.f, 2)
    DO_SIDE_STATS(3, 2, EY,  1.f, 5)

    __syncthreads();
    if (tid < 6)
        atomicAdd(&sum[tid * 64 + c], redS[0][tid] + redS[1][tid] + redS[2][tid] + redS[3][tid]);
    else if (tid < 12) {
        int v = tid - 6;
        atomicAdd(&sqs[v * 64 + c], redQ[0][v] + redQ[1][v] + redQ[2][v] + redQ[3][v]);
    }
}

__global__ void k_alpha(const float* __restrict__ sum, const float* __restrict__ sqs,
                        const float* __restrict__ bn_ge,
                        const float* __restrict__ bn_gd,
                        const float* __restrict__ conve,
                        const float* __restrict__ convd,
                        float* __restrict__ alpha) {
    int tid = threadIdx.x;
    if (tid >= 384) return;
    float mean = sum[tid] * (1.0f / N1);
    float var  = sqs[tid] * (1.0f / N1) - mean * mean;
    float inv  = rsqrtf(fmaxf(var, 0.f) + EPSB);
    float g, cw, sgn;
    if (tid < 192) { g = bn_ge[tid];       cw = conve[tid];       sgn = -1.f; }
    else           { g = bn_gd[tid - 192]; cw = convd[tid - 192]; sgn =  1.f; }
    // ln2 folded so pass 2 can use __log2f directly
    alpha[tid] = sgn * cw * g * inv * INV_BETA * LN2;
}

// USE_PART=1: plain stores to chunk-private partial slabs (no atomics).
// USE_PART=0: R2 atomic-accumulate fallback (used when ws_size is too small).
template<int USE_PART>
__global__ __launch_bounds__(256, 7) void k_reduce_c_t(
    const float* __restrict__ x, const float* __restrict__ wg,
    const float* __restrict__ alpha, float* __restrict__ ye, float* __restrict__ yd,
    float* __restrict__ pe, float* __restrict__ pd) {
    __shared__ float EX[PLANE], EY[PLANE];
    const int tid = threadIdx.x;
    const int t = blockIdx.x;             // 18 tiles
    const int bz = blockIdx.y;            // b*8 + chunk
    const int b = bz >> 3, chunk = bz & 7;
    const int h0 = (t / NTW) * TILE_H, w0 = (t % NTW) * TILE_W;
    const int px = (tid & 31) + HALO;
    const int py0 = (tid >> 5) * 8;
    float accE[8] = {0,0,0,0,0,0,0,0}, accD[8] = {0,0,0,0,0,0,0,0};

    for (int ci = 0; ci < 8; ++ci) {
        const int c = chunk * 8 + ci;
        __syncthreads();
        load_tile(x + (size_t)(b * 64 + c) * HWn, EX, EY, h0, w0, tid);
        __syncthreads();

#define DO_SIDE_ACC(D, PL, SLOT, ACC) { \
        float S[8]; \
        sweep<D>(PL, py0, px, wg + (SLOT)*576 + c*9, S); \
        const float a_ = alpha[(SLOT)*64 + c]; \
        _Pragma("unroll") \
        for (int k = 0; k < 8; ++k) \
            ACC[k] = fmaf(a_, __log2f(fmaxf(S[k], SFLOOR)), ACC[k]); }

        DO_SIDE_ACC(1, EX, 0, accE)
        DO_SIDE_ACC(1, EY, 3, accD)
        DO_SIDE_ACC(2, EX, 1, accE)
        DO_SIDE_ACC(2, EY, 4, accD)
        DO_SIDE_ACC(3, EX, 2, accE)
        DO_SIDE_ACC(3, EY, 5, accD)
    }
    if (USE_PART) {
        const size_t sbase = (size_t)(chunk * 8 + b) * HWn;
#pragma unroll
        for (int k = 0; k < 8; ++k) {
            int rem = (h0 + py0 + k) * Wn + (w0 + px - HALO);
            pe[sbase + rem] = accE[k];
            pd[sbase + rem] = accD[k];
        }
    } else {
#pragma unroll
        for (int k = 0; k < 8; ++k) {
            int idx = b * HWn + (h0 + py0 + k) * Wn + (w0 + px - HALO);
            atomicAdd(&ye[idx], accE[k]);
            atomicAdd(&yd[idx], accD[k]);
        }
    }
}

// Partial-path fstats: sum 8 chunk slabs per pixel, emit final ye/yd + scalar stats.
__global__ __launch_bounds__(256) void k_fstats_p(
    const float* __restrict__ pe, const float* __restrict__ pd,
    float* __restrict__ ye, float* __restrict__ yd, float* __restrict__ scal) {
    int i = blockIdx.x * 256 + threadIdx.x;   // < 294912
    int b = i / HWn, rem = i - b * HWn;
    float e = 0.f, d = 0.f;
#pragma unroll
    for (int ch = 0; ch < 8; ++ch) {
        e += pe[(size_t)(ch * 8 + b) * HWn + rem];
        d += pd[(size_t)(ch * 8 + b) * HWn + rem];
    }
    ye[i] = e; yd[i] = d;
    float v[4] = {e, e * e, d, d * d};
    __shared__ float red[4][4];
    int lane = threadIdx.x & 63, wv = threadIdx.x >> 6;
#pragma unroll
    for (int k = 0; k < 4; ++k) {
        float tv = v[k];
#pragma unroll
        for (int off = 32; off; off >>= 1) tv += __shfl_down(tv, off, 64);
        if (lane == 0) red[wv][k] = tv;
    }
    __syncthreads();
    if (threadIdx.x < 4)
        atomicAdd(&scal[threadIdx.x],
                  red[0][threadIdx.x] + red[1][threadIdx.x] + red[2][threadIdx.x] + red[3][threadIdx.x]);
}

__global__ __launch_bounds__(256) void k_fstats(const float* __restrict__ ye,
                                                const float* __restrict__ yd,
                                                float* __restrict__ scal) {
    int i = blockIdx.x * 256 + threadIdx.x;
    float a = ye[i], b = yd[i];
    float v[4] = {a, a * a, b, b * b};
    __shared__ float red[4][4];
    int lane = threadIdx.x & 63, wv = threadIdx.x >> 6;
#pragma unroll
    for (int k = 0; k < 4; ++k) {
        float tv = v[k];
#pragma unroll
        for (int off = 32; off; off >>= 1) tv += __shfl_down(tv, off, 64);
        if (lane == 0) red[wv][k] = tv;
    }
    __syncthreads();
    if (threadIdx.x < 4)
        atomicAdd(&scal[threadIdx.x],
                  red[0][threadIdx.x] + red[1][threadIdx.x] + red[2][threadIdx.x] + red[3][threadIdx.x]);
}

__global__ __launch_bounds__(256) void k_final(
    const float* __restrict__ ye, const float* __restrict__ yd,
    const float* __restrict__ scal,
    const float* __restrict__ g_e, const float* __restrict__ b_e,
    const float* __restrict__ g_d, const float* __restrict__ b_d,
    float* __restrict__ out) {
    int i = blockIdx.x * 256 + threadIdx.x;  // < 294912
    float me_ = scal[0] * (1.0f / N1);
    float ve  = scal[1] * (1.0f / N1) - me_ * me_;
    float ie  = rsqrtf(fmaxf(ve, 0.f) + EPSB);
    float md_ = scal[2] * (1.0f / N1);
    float vd  = scal[3] * (1.0f / N1) - md_ * md_;
    float idv = rsqrtf(fmaxf(vd, 0.f) + EPSB);
    float ge = g_e[0], be = b_e[0];
    float gd = g_d[0], bd = b_d[0];
    int b = i / HWn, rem = i - b * HWn;
    float oe = fmaxf(ge * (ye[i] - me_) * ie + be, 0.f);
    float od = fmaxf(gd * (yd[i] - md_) * idv + bd, 0.f);
    out[(size_t)(b * 2) * HWn + rem]     = oe;
    out[(size_t)(b * 2 + 1) * HWn + rem] = od;
}

extern "C" void kernel_launch(void* const* d_in, const int* in_sizes, int n_in,
                              void* d_out, int out_size, void* d_ws, size_t ws_size,
                              hipStream_t stream) {
    const float* x     = (const float*)d_in[0];
    const float* we    = (const float*)d_in[1];
    const float* wd    = (const float*)d_in[2];
    const float* bn_ge = (const float*)d_in[3];
    const float* bn_gd = (const float*)d_in[5];
    const float* conve = (const float*)d_in[7];
    const float* convd = (const float*)d_in[8];
    const float* g_e   = (const float*)d_in[9];
    const float* b_e   = (const float*)d_in[10];
    const float* g_d   = (const float*)d_in[11];
    const float* b_d   = (const float*)d_in[12];
    float* ws = (float*)d_ws;

    const bool part = ws_size >= (size_t)WS_TOTAL_P * sizeof(float);

    if (part) {
        // only sum/sqs/scal need zeroing (772 floats); partial slabs fully overwritten
        hipMemsetAsync(d_ws, 0, 772 * sizeof(float), stream);
    } else {
        hipMemsetAsync(d_ws, 0, (size_t)WS_TOTAL * sizeof(float), stream);
    }
    hipLaunchKernelGGL(k_wexp, dim3(14), dim3(256), 0, stream, we, wd, ws + WS_WG);
    hipLaunchKernelGGL(k_morph_stats, dim3(NTILES, 512), dim3(256), 0, stream,
                       x, ws + WS_WG, ws + WS_SUM, ws + WS_SQS);
    hipLaunchKernelGGL(k_alpha, dim3(1), dim3(384), 0, stream,
                       ws + WS_SUM, ws + WS_SQS, bn_ge, bn_gd, conve, convd, ws + WS_ALPHA);
    if (part) {
        hipLaunchKernelGGL((k_reduce_c_t<1>), dim3(NTILES, 64), dim3(256), 0, stream,
                           x, ws + WS_WG, ws + WS_ALPHA, ws + WS_YE, ws + WS_YD,
                           ws + WS_PE, ws + WS_PD);
        hipLaunchKernelGGL(k_fstats_p, dim3(1152), dim3(256), 0, stream,
                           ws + WS_PE, ws + WS_PD, ws + WS_YE, ws + WS_YD, ws + WS_SCAL);
    } else {
        hipLaunchKernelGGL((k_reduce_c_t<0>), dim3(NTILES, 64), dim3(256), 0, stream,
                           x, ws + WS_WG, ws + WS_ALPHA, ws + WS_YE, ws + WS_YD,
                           (float*)nullptr, (float*)nullptr);
        hipLaunchKernelGGL(k_fstats, dim3(1152), dim3(256), 0, stream,
                           ws + WS_YE, ws + WS_YD, ws + WS_SCAL);
    }
    hipLaunchKernelGGL(k_final, dim3(1152), dim3(256), 0, stream,
                       ws + WS_YE, ws + WS_YD, ws + WS_SCAL, g_e, b_e, g_d, b_d,
                       (float*)d_out);
}

// Round 4
// 372.411 us; speedup vs baseline: 1.0775x; 1.0775x over previous
//
#include <hip/hip_runtime.h>

// DEChannelPool: 6 soft-morphology branches + per-channel BN + 1x1 conv + BN + ReLU.
// Trick 1: exp(beta*(w±x)) = exp(beta*w)*exp(±beta*x): 2 exps per input pixel (shifted
//          by M for fp32 range), reused across all taps/branches.
// Trick 2: BN+conv fold to alpha*log2(S) + const; const cancels in the final scalar BN.
// R4: side-split everywhere; k_reduce loops all 64 channels per block -> plain stores
//     (atomics were ~93 B/op of HBM RMW = the 130 us tax); register prefetch of next
//     channel overlaps sweeps; fstats folded into reduce epilogue; stats kernel at
//     8 blocks/CU (one E-plane, 10.9 KB LDS).

#define BETA 15.0f
#define MSHIFT 25.0f
#define INV_BETA (1.0f/15.0f)
#define LN2 0.6931471805599453f
#define EPSB 1e-5f
#define Hn 192
#define Wn 192
#define HWn (192*192)
#define N1 (8*192*192)
#define HALO 3
#define SFLOOR 1e-37f

// ---- stats kernel geometry: 64r x 32c tile, h=8 strips, 256 thr, one side ----
#define STDH 70
#define STW 38
#define STSTR 39            // 8*39 % 32 = 24 -> 2-way strip aliasing (free)
#define STNL (STDH*STW)     // 2660

// ---- reduce kernel geometry: 32r x 16c tile, h=4 strips, 128 thr, one side ----
#define RDH 38
#define RW 22
#define RSTR 26             // 4*26 % 32 = 8 -> strip banks {0,8,16,24}, 2-way (free)
#define RNL (RDH*RW)        // 836

// workspace layout (float offsets)
#define WS_SUM   0
#define WS_SQS   384
#define WS_SCAL  768
#define WS_ALPHA 772
#define WS_WG    1156
#define WS_YE    4612
#define WS_YD    (4612 + 294912)
#define WS_TOTAL (4612 + 2*294912)

__global__ void k_wexp(const float* __restrict__ we,
                       const float* __restrict__ wd,
                       float* __restrict__ wg) {
    int idx = blockIdx.x * 256 + threadIdx.x;
    if (idx >= 3456) return;
    int kb = idx / 576;            // 0..5 (0-2 erosion, 3-5 dilation)
    int rem = idx - kb * 576;      // c*9 + tap
    float w = (kb < 3) ? we[kb * 576 + rem] : wd[(kb - 3) * 576 + rem];
    wg[idx] = __expf(BETA * w);
}

// Register-rotating stencil over one plane. Each b32 read feeds up to 3 of the H
// output accumulators. All offsets literal after unroll.
template<int D, int H, int STR>
__device__ __forceinline__ void sweepT(const float* __restrict__ P,
                                       int py0, int px,
                                       const float* __restrict__ wgp,
                                       float* __restrict__ S) {
    float W[9];
#pragma unroll
    for (int k2 = 0; k2 < 9; ++k2) W[k2] = wgp[k2];
#pragma unroll
    for (int k = 0; k < H; ++k) S[k] = 0.f;
    const float* base = P + (py0 - D + HALO) * STR + (px - D);
#pragma unroll
    for (int r = 0; r < H + 2 * D; ++r) {
        float va = base[r * STR];
        float vb = base[r * STR + D];
        float vc = base[r * STR + 2 * D];
#pragma unroll
        for (int i = 0; i < 3; ++i) {
            int k = r - i * D;            // output row fed by input row r via weight-row i
            if (k >= 0 && k < H) {
                S[k] = fmaf(W[i*3+0], va, S[k]);
                S[k] = fmaf(W[i*3+1], vb, S[k]);
                S[k] = fmaf(W[i*3+2], vc, S[k]);
            }
        }
    }
}

__device__ __forceinline__ void red2(float a, float b2, int lane, float* rs, float* rq) {
#pragma unroll
    for (int off = 32; off; off >>= 1) {
        a  += __shfl_down(a, off, 64);
        b2 += __shfl_down(b2, off, 64);
    }
    if (lane == 0) { *rs = a; *rq = b2; }
}

// grid (18 tiles, 512 b*c, 2 sides), 256 threads. One side per block -> one plane.
__global__ __launch_bounds__(256, 8) void k_morph_stats(
    const float* __restrict__ x, const float* __restrict__ wg,
    float* __restrict__ sum, float* __restrict__ sqs) {
    __shared__ float E[STDH * STSTR];
    __shared__ float redS[4][3], redQ[4][3];
    const int tid = threadIdx.x;
    const int p = blockIdx.y;            // b*64 + c
    const int c = p & 63;
    const int t = blockIdx.x;
    const int side = blockIdx.z;         // 0 = erosion, 1 = dilation
    const int h0 = (t / 6) * 64, w0 = (t % 6) * 32;
    const float sb = side ? BETA : -BETA;
    const float* xp = x + (size_t)p * HWn;
    const float em0 = __expf(-MSHIFT);

    {
        int r = tid / STW, cc = tid - r * STW;
        for (int l = tid; l < STNL; l += 256) {
            int gh = h0 - HALO + r, gw = w0 - HALO + cc;
            float e = em0;
            if ((unsigned)gh < (unsigned)Hn && (unsigned)gw < (unsigned)Wn)
                e = __expf(sb * xp[gh * Wn + gw] - MSHIFT);
            E[r * STSTR + cc] = e;
            r += 6; cc += 28;             // 256 = 6*38 + 28
            if (cc >= STW) { cc -= STW; ++r; }
        }
    }
    __syncthreads();

    const int px = (tid & 31) + HALO;
    const int py0 = (tid >> 5) * 8;
    const int lane = tid & 63, wv = tid >> 6;
    const float aL = side ? (LN2 * INV_BETA) : -(LN2 * INV_BETA);
    const float aM = side ? (MSHIFT * INV_BETA) : -(MSHIFT * INV_BETA);
    const float* wgs = wg + side * 3 * 576 + c * 9;

#define DO_BR_STATS(D, BR) { \
    float S[8]; \
    sweepT<D, 8, STSTR>(E, py0, px, wgs + (BR) * 576, S); \
    float sv = 0.f, qv = 0.f; \
    _Pragma("unroll") \
    for (int k = 0; k < 8; ++k) { \
        float m = fmaf(__log2f(fmaxf(S[k], SFLOOR)), aL, aM); \
        sv += m; qv = fmaf(m, m, qv); \
    } \
    red2(sv, qv, lane, &redS[wv][BR], &redQ[wv][BR]); }

    DO_BR_STATS(1, 0)
    DO_BR_STATS(2, 1)
    DO_BR_STATS(3, 2)

    __syncthreads();
    if (tid < 3)
        atomicAdd(&sum[(side * 3 + tid) * 64 + c],
                  redS[0][tid] + redS[1][tid] + redS[2][tid] + redS[3][tid]);
    else if (tid < 6) {
        int v = tid - 3;
        atomicAdd(&sqs[(side * 3 + v) * 64 + c],
                  redQ[0][v] + redQ[1][v] + redQ[2][v] + redQ[3][v]);
    }
}

__global__ void k_alpha(const float* __restrict__ sum, const float* __restrict__ sqs,
                        const float* __restrict__ bn_ge,
                        const float* __restrict__ bn_gd,
                        const float* __restrict__ conve,
                        const float* __restrict__ convd,
                        float* __restrict__ alpha) {
    int tid = threadIdx.x;
    if (tid >= 384) return;
    float mean = sum[tid] * (1.0f / N1);
    float var  = sqs[tid] * (1.0f / N1) - mean * mean;
    float inv  = rsqrtf(fmaxf(var, 0.f) + EPSB);
    float g, cw, sgn;
    if (tid < 192) { g = bn_ge[tid];       cw = conve[tid];       sgn = -1.f; }
    else           { g = bn_gd[tid - 192]; cw = convd[tid - 192]; sgn =  1.f; }
    alpha[tid] = sgn * cw * g * inv * INV_BETA * LN2;
}

// grid (72 tiles, 8 b, 2 sides), 128 threads. Block owns its pixel tile for ALL 64
// channels of one side -> complete sum -> plain store. Next-channel loads prefetched
// into registers during sweeps. Scalar BN stats reduced in the epilogue.
__global__ __launch_bounds__(128, 4) void k_reduce(
    const float* __restrict__ x, const float* __restrict__ wg,
    const float* __restrict__ alpha,
    float* __restrict__ ye, float* __restrict__ yd, float* __restrict__ scal) {
    __shared__ float E[RDH * RSTR];
    __shared__ float redA[2][2];
    const int tid = threadIdx.x;
    const int t = blockIdx.x;             // 72 = 6 row-tiles * 12 col-tiles
    const int b = blockIdx.y;
    const int side = blockIdx.z;
    const int tr = t / 12, tc = t - tr * 12;
    const int h0 = tr * 32, w0 = tc * 16;
    const int px = (tid & 15) + HALO;
    const int py0 = (tid >> 4) * 4;
    const float sb = side ? BETA : -BETA;
    const float* xb = x + (size_t)b * 64 * HWn;
    const float* wgs = wg + side * 3 * 576;
    const float* als = alpha + side * 3 * 64;
    float acc[4] = {0.f, 0.f, 0.f, 0.f};
    float L[7];

    // prologue: prefetch channel 0 into registers
    {
        int r = tid / RW, cc = tid - r * RW;
#pragma unroll
        for (int i = 0; i < 7; ++i) {
            int l = tid + i * 128;
            float v = 0.f;
            if (l < RNL) {
                int gh = h0 - HALO + r, gw = w0 - HALO + cc;
                if ((unsigned)gh < (unsigned)Hn && (unsigned)gw < (unsigned)Wn)
                    v = xb[gh * Wn + gw];
            }
            L[i] = v;
            r += 5; cc += 18;             // 128 = 5*22 + 18
            if (cc >= RW) { cc -= RW; ++r; }
        }
    }

    for (int ci = 0; ci < 64; ++ci) {
        __syncthreads();                  // tile buffer free
        {   // write phase: exp + ds_write (pad/OOB loaded as 0 -> exp(-M), correct)
            int r = tid / RW, cc = tid - r * RW;
#pragma unroll
            for (int i = 0; i < 7; ++i) {
                int l = tid + i * 128;
                if (l < RNL) E[r * RSTR + cc] = __expf(sb * L[i] - MSHIFT);
                r += 5; cc += 18;
                if (cc >= RW) { cc -= RW; ++r; }
            }
        }
        __syncthreads();
        if (ci < 63) {                    // prefetch next channel (overlaps sweeps)
            const float* xp = xb + (size_t)(ci + 1) * HWn;
            int r = tid / RW, cc = tid - r * RW;
#pragma unroll
            for (int i = 0; i < 7; ++i) {
                int l = tid + i * 128;
                float v = 0.f;
                if (l < RNL) {
                    int gh = h0 - HALO + r, gw = w0 - HALO + cc;
                    if ((unsigned)gh < (unsigned)Hn && (unsigned)gw < (unsigned)Wn)
                        v = xp[gh * Wn + gw];
                }
                L[i] = v;
                r += 5; cc += 18;
                if (cc >= RW) { cc -= RW; ++r; }
            }
        }
        {
            float S[4];
            sweepT<1, 4, RSTR>(E, py0, px, wgs + ci * 9, S);
            const float a0 = als[ci];
#pragma unroll
            for (int k = 0; k < 4; ++k)
                acc[k] = fmaf(a0, __log2f(fmaxf(S[k], SFLOOR)), acc[k]);
            sweepT<2, 4, RSTR>(E, py0, px, wgs + 576 + ci * 9, S);
            const float a1 = als[64 + ci];
#pragma unroll
            for (int k = 0; k < 4; ++k)
                acc[k] = fmaf(a1, __log2f(fmaxf(S[k], SFLOOR)), acc[k]);
            sweepT<3, 4, RSTR>(E, py0, px, wgs + 2 * 576 + ci * 9, S);
            const float a2 = als[128 + ci];
#pragma unroll
            for (int k = 0; k < 4; ++k)
                acc[k] = fmaf(a2, __log2f(fmaxf(S[k], SFLOOR)), acc[k]);
        }
    }

    float* yo = side ? yd : ye;
#pragma unroll
    for (int k = 0; k < 4; ++k)
        yo[b * HWn + (h0 + py0 + k) * Wn + (w0 + px - HALO)] = acc[k];

    // scalar BN stats (replaces k_fstats)
    float s = acc[0] + acc[1] + acc[2] + acc[3];
    float q = fmaf(acc[0], acc[0], fmaf(acc[1], acc[1],
              fmaf(acc[2], acc[2], acc[3] * acc[3])));
    const int lane = tid & 63, wv = tid >> 6;
#pragma unroll
    for (int off = 32; off; off >>= 1) {
        s += __shfl_down(s, off, 64);
        q += __shfl_down(q, off, 64);
    }
    if (lane == 0) { redA[wv][0] = s; redA[wv][1] = q; }
    __syncthreads();
    if (tid == 0) {
        atomicAdd(&scal[side * 2 + 0], redA[0][0] + redA[1][0]);
        atomicAdd(&scal[side * 2 + 1], redA[0][1] + redA[1][1]);
    }
}

__global__ __launch_bounds__(256) void k_final(
    const float* __restrict__ ye, const float* __restrict__ yd,
    const float* __restrict__ scal,
    const float* __restrict__ g_e, const float* __restrict__ b_e,
    const float* __restrict__ g_d, const float* __restrict__ b_d,
    float* __restrict__ out) {
    int i = blockIdx.x * 256 + threadIdx.x;  // < 294912
    float me_ = scal[0] * (1.0f / N1);
    float ve  = scal[1] * (1.0f / N1) - me_ * me_;
    float ie  = rsqrtf(fmaxf(ve, 0.f) + EPSB);
    float md_ = scal[2] * (1.0f / N1);
    float vd  = scal[3] * (1.0f / N1) - md_ * md_;
    float idv = rsqrtf(fmaxf(vd, 0.f) + EPSB);
    float ge = g_e[0], be = b_e[0];
    float gd = g_d[0], bd = b_d[0];
    int b = i / HWn, rem = i - b * HWn;
    float oe = fmaxf(ge * (ye[i] - me_) * ie + be, 0.f);
    float od = fmaxf(gd * (yd[i] - md_) * idv + bd, 0.f);
    out[(size_t)(b * 2) * HWn + rem]     = oe;
    out[(size_t)(b * 2 + 1) * HWn + rem] = od;
}

extern "C" void kernel_launch(void* const* d_in, const int* in_sizes, int n_in,
                              void* d_out, int out_size, void* d_ws, size_t ws_size,
                              hipStream_t stream) {
    const float* x     = (const float*)d_in[0];
    const float* we    = (const float*)d_in[1];
    const float* wd    = (const float*)d_in[2];
    const float* bn_ge = (const float*)d_in[3];
    const float* bn_gd = (const float*)d_in[5];
    const float* conve = (const float*)d_in[7];
    const float* convd = (const float*)d_in[8];
    const float* g_e   = (const float*)d_in[9];
    const float* b_e   = (const float*)d_in[10];
    const float* g_d   = (const float*)d_in[11];
    const float* b_d   = (const float*)d_in[12];
    float* ws = (float*)d_ws;

    // only sum/sqs/scal need zeroing; wg/alpha/ye/yd are fully overwritten
    hipMemsetAsync(d_ws, 0, 772 * sizeof(float), stream);
    hipLaunchKernelGGL(k_wexp, dim3(14), dim3(256), 0, stream, we, wd, ws + WS_WG);
    hipLaunchKernelGGL(k_morph_stats, dim3(18, 512, 2), dim3(256), 0, stream,
                       x, ws + WS_WG, ws + WS_SUM, ws + WS_SQS);
    hipLaunchKernelGGL(k_alpha, dim3(1), dim3(384), 0, stream,
                       ws + WS_SUM, ws + WS_SQS, bn_ge, bn_gd, conve, convd, ws + WS_ALPHA);
    hipLaunchKernelGGL(k_reduce, dim3(72, 8, 2), dim3(128), 0, stream,
                       x, ws + WS_WG, ws + WS_ALPHA, ws + WS_YE, ws + WS_YD, ws + WS_SCAL);
    hipLaunchKernelGGL(k_final, dim3(1152), dim3(256), 0, stream,
                       ws + WS_YE, ws + WS_YD, ws + WS_SCAL, g_e, b_e, g_d, b_d,
                       (float*)d_out);
}